// Round 1
// baseline (494.424 us; speedup 1.0000x reference)
//
#include <hip/hip_runtime.h>

#define NN 100000
#define NE 1600000

// ---------------- degree count ----------------
__global__ __launch_bounds__(256) void k_count_deg(const int* __restrict__ dst, int* __restrict__ deg) {
    int i = blockIdx.x * 256 + threadIdx.x;
    if (i < NE) atomicAdd(&deg[dst[i]], 1);
}

// ---------------- 3-phase exclusive scan of deg -> offsets ----------------
__global__ __launch_bounds__(256) void k_scan_partial(const int* __restrict__ deg, int* __restrict__ partial) {
    __shared__ int sd[256];
    int i = blockIdx.x * 256 + threadIdx.x;
    sd[threadIdx.x] = (i < NN) ? deg[i] : 0;
    __syncthreads();
    for (int s = 128; s > 0; s >>= 1) {
        if (threadIdx.x < s) sd[threadIdx.x] += sd[threadIdx.x + s];
        __syncthreads();
    }
    if (threadIdx.x == 0) partial[blockIdx.x] = sd[0];
}

__global__ __launch_bounds__(512) void k_scan_block(int* __restrict__ partial, int nb) {
    __shared__ int s[512];
    int t = threadIdx.x;
    s[t] = (t < nb) ? partial[t] : 0;
    __syncthreads();
    for (int off = 1; off < 512; off <<= 1) {
        int add = (t >= off) ? s[t - off] : 0;
        __syncthreads();
        s[t] += add;
        __syncthreads();
    }
    if (t < nb) partial[t] = s[t];
}

__global__ __launch_bounds__(256) void k_scan_final(const int* __restrict__ deg, const int* __restrict__ partialScan,
                                                   int* __restrict__ offsets, int* __restrict__ cursor,
                                                   float* __restrict__ inv_deg) {
    __shared__ int s[256];
    int b = blockIdx.x, t = threadIdx.x;
    int i = b * 256 + t;
    int v = (i < NN) ? deg[i] : 0;
    s[t] = v;
    __syncthreads();
    for (int off = 1; off < 256; off <<= 1) {
        int add = (t >= off) ? s[t - off] : 0;
        __syncthreads();
        s[t] += add;
        __syncthreads();
    }
    if (i < NN) {
        int base = (b > 0) ? partialScan[b - 1] : 0;
        int excl = base + s[t] - v;
        offsets[i] = excl;
        cursor[i] = excl;
        inv_deg[i] = (v > 0) ? (1.0f / (float)v) : 0.0f;
        if (i == NN - 1) offsets[NN] = excl + v;
    }
}

// ---------------- CSR fill (counting sort by dst) ----------------
__global__ __launch_bounds__(256) void k_fill_csr(const int* __restrict__ src, const int* __restrict__ dst,
                                                  int* __restrict__ cursor, int* __restrict__ sorted_src) {
    int i = blockIdx.x * 256 + threadIdx.x;
    if (i < NE) {
        int d = dst[i];
        int p = atomicAdd(&cursor[d], 1);
        sorted_src[p] = src[i];
    }
}

// ---------------- mean aggregation: one wave per node, lane = feature ----------------
__global__ __launch_bounds__(256) void k_aggregate(const float* __restrict__ feat, const int* __restrict__ sorted_src,
                                                   const int* __restrict__ offsets, const float* __restrict__ inv_deg,
                                                   float* __restrict__ out) {
    int node = blockIdx.x * 4 + (threadIdx.x >> 6);
    int lane = threadIdx.x & 63;
    if (node >= NN) return;
    int beg = offsets[node], end = offsets[node + 1];
    float acc = 0.f;
    int e = beg;
    for (; e + 3 < end; e += 4) {
        int s0 = sorted_src[e], s1 = sorted_src[e + 1], s2 = sorted_src[e + 2], s3 = sorted_src[e + 3];
        acc += feat[(size_t)s0 * 64 + lane];
        acc += feat[(size_t)s1 * 64 + lane];
        acc += feat[(size_t)s2 * 64 + lane];
        acc += feat[(size_t)s3 * 64 + lane];
    }
    for (; e < end; e++) acc += feat[(size_t)sorted_src[e] * 64 + lane];
    out[(size_t)node * 64 + lane] = acc * inv_deg[node];
}

// ---------------- fused dual GEMM: out = relu(A1@W1 + b + A2@W2), optional @Wfc+bfc head ----------------
// Block: 256 threads, tile 64 nodes x 64 outputs, thread = 4x4 micro-tile.
template <bool FUSE_HEAD>
__global__ __launch_bounds__(256) void k_linear(const float* __restrict__ A1, const float* __restrict__ A2,
                                                const float* __restrict__ W1, const float* __restrict__ W2,
                                                const float* __restrict__ bias,
                                                const float* __restrict__ Wfc, const float* __restrict__ bfc,
                                                float* __restrict__ out) {
    __shared__ __align__(16) float sA1[64 * 65];
    __shared__ __align__(16) float sA2[64 * 65];
    __shared__ __align__(16) float sW1[64 * 64];
    __shared__ __align__(16) float sW2[64 * 64];
    __shared__ float sB[64];
    __shared__ float sWfc[64];
    __shared__ float sRed[64 * 17];

    int tid = threadIdx.x;
    int i0 = blockIdx.x * 64;

#pragma unroll
    for (int r = 0; r < 4; r++) {
        int idx = r * 1024 + tid * 4;
        *(float4*)&sW1[idx] = *(const float4*)&W1[idx];
        *(float4*)&sW2[idx] = *(const float4*)&W2[idx];
    }
    if (tid < 64) {
        sB[tid] = bias[tid];
        sWfc[tid] = FUSE_HEAD ? Wfc[tid] : 0.f;
    }

    int col4 = (tid & 15) * 4;
#pragma unroll
    for (int rep = 0; rep < 4; rep++) {
        int r = rep * 16 + (tid >> 4);
        int g = i0 + r;
        float4 v1 = {0, 0, 0, 0}, v2 = {0, 0, 0, 0};
        if (g < NN) {
            v1 = *(const float4*)&A1[(size_t)g * 64 + col4];
            v2 = *(const float4*)&A2[(size_t)g * 64 + col4];
        }
        sA1[r * 65 + col4 + 0] = v1.x; sA1[r * 65 + col4 + 1] = v1.y;
        sA1[r * 65 + col4 + 2] = v1.z; sA1[r * 65 + col4 + 3] = v1.w;
        sA2[r * 65 + col4 + 0] = v2.x; sA2[r * 65 + col4 + 1] = v2.y;
        sA2[r * 65 + col4 + 2] = v2.z; sA2[r * 65 + col4 + 3] = v2.w;
    }
    __syncthreads();

    int tj = tid & 15;
    int ti = tid >> 4;
    float acc[4][4] = {};
    const float4* W1f = (const float4*)sW1;
    const float4* W2f = (const float4*)sW2;
#pragma unroll 8
    for (int k = 0; k < 64; k++) {
        float4 w1 = W1f[k * 16 + tj];
        float4 w2 = W2f[k * 16 + tj];
#pragma unroll
        for (int d = 0; d < 4; d++) {
            float a1 = sA1[(ti * 4 + d) * 65 + k];
            float a2 = sA2[(ti * 4 + d) * 65 + k];
            acc[d][0] += a1 * w1.x; acc[d][0] += a2 * w2.x;
            acc[d][1] += a1 * w1.y; acc[d][1] += a2 * w2.y;
            acc[d][2] += a1 * w1.z; acc[d][2] += a2 * w2.z;
            acc[d][3] += a1 * w1.w; acc[d][3] += a2 * w2.w;
        }
    }

    if (!FUSE_HEAD) {
#pragma unroll
        for (int d = 0; d < 4; d++) {
            int g = i0 + ti * 4 + d;
            if (g < NN) {
                float4 o;
                o.x = fmaxf(acc[d][0] + sB[tj * 4 + 0], 0.f);
                o.y = fmaxf(acc[d][1] + sB[tj * 4 + 1], 0.f);
                o.z = fmaxf(acc[d][2] + sB[tj * 4 + 2], 0.f);
                o.w = fmaxf(acc[d][3] + sB[tj * 4 + 3], 0.f);
                *(float4*)&out[(size_t)g * 64 + tj * 4] = o;
            }
        }
    } else {
#pragma unroll
        for (int d = 0; d < 4; d++) {
            float psum = 0.f;
            psum += fmaxf(acc[d][0] + sB[tj * 4 + 0], 0.f) * sWfc[tj * 4 + 0];
            psum += fmaxf(acc[d][1] + sB[tj * 4 + 1], 0.f) * sWfc[tj * 4 + 1];
            psum += fmaxf(acc[d][2] + sB[tj * 4 + 2], 0.f) * sWfc[tj * 4 + 2];
            psum += fmaxf(acc[d][3] + sB[tj * 4 + 3], 0.f) * sWfc[tj * 4 + 3];
            sRed[(ti * 4 + d) * 17 + tj] = psum;
        }
        __syncthreads();
        if (tid < 64) {
            float sum = bfc[0];
#pragma unroll
            for (int c = 0; c < 16; c++) sum += sRed[tid * 17 + c];
            int g = i0 + tid;
            if (g < NN) out[g] = sum;
        }
    }
}

extern "C" void kernel_launch(void* const* d_in, const int* in_sizes, int n_in,
                              void* d_out, int out_size, void* d_ws, size_t ws_size,
                              hipStream_t stream) {
    const float* x   = (const float*)d_in[0];
    const int*   ei  = (const int*)d_in[1];
    const float* Wl1 = (const float*)d_in[2];
    const float* bl1 = (const float*)d_in[3];
    const float* Wr1 = (const float*)d_in[4];
    const float* Wl2 = (const float*)d_in[5];
    const float* bl2 = (const float*)d_in[6];
    const float* Wr2 = (const float*)d_in[7];
    const float* Wfc = (const float*)d_in[8];
    const float* bfc = (const float*)d_in[9];
    float* out = (float*)d_out;

    const int* src = ei;       // edge_index[0]
    const int* dst = ei + NE;  // edge_index[1]

    char* p = (char*)d_ws;
    auto carve = [&](size_t bytes) {
        char* q = p;
        p += (bytes + 255) & ~size_t(255);
        return q;
    };
    int*   deg     = (int*)carve((size_t)NN * 4);
    int*   cursor  = (int*)carve((size_t)NN * 4);
    int*   offsets = (int*)carve((size_t)(NN + 1) * 4);
    int*   partial = (int*)carve(512 * 4);
    float* inv_deg = (float*)carve((size_t)NN * 4);
    int*   ssrc    = (int*)carve((size_t)NE * 4);
    float* agg     = (float*)carve((size_t)NN * 64 * 4);
    float* h1      = (float*)carve((size_t)NN * 64 * 4);

    const int ebl = (NE + 255) / 256;   // 6250
    const int nbl = (NN + 255) / 256;   // 391

    hipMemsetAsync(deg, 0, (size_t)NN * 4, stream);
    k_count_deg<<<ebl, 256, 0, stream>>>(dst, deg);
    k_scan_partial<<<nbl, 256, 0, stream>>>(deg, partial);
    k_scan_block<<<1, 512, 0, stream>>>(partial, nbl);
    k_scan_final<<<nbl, 256, 0, stream>>>(deg, partial, offsets, cursor, inv_deg);
    k_fill_csr<<<ebl, 256, 0, stream>>>(src, dst, cursor, ssrc);

    // layer 1
    k_aggregate<<<(NN + 3) / 4, 256, 0, stream>>>(x, ssrc, offsets, inv_deg, agg);
    k_linear<false><<<(NN + 63) / 64, 256, 0, stream>>>(agg, x, Wl1, Wr1, bl1, Wfc, bfc, h1);
    // layer 2 + fused head
    k_aggregate<<<(NN + 3) / 4, 256, 0, stream>>>(h1, ssrc, offsets, inv_deg, agg);
    k_linear<true><<<(NN + 63) / 64, 256, 0, stream>>>(agg, h1, Wl2, Wr2, bl2, Wfc, bfc, out);
}

// Round 2
// 393.969 us; speedup vs baseline: 1.2550x; 1.2550x over previous
//
#include <hip/hip_runtime.h>

#define NN 100000
#define NE 1600000

// ---------------- degree count + per-edge rank (rank = atomic return) ----------------
__global__ __launch_bounds__(256) void k_count_rank(const int* __restrict__ dst, int* __restrict__ deg,
                                                    unsigned short* __restrict__ rank) {
    int base = blockIdx.x * 1024 + threadIdx.x;
#pragma unroll
    for (int k = 0; k < 4; k++) {
        int i = base + k * 256;
        if (i < NE) {
            int r = atomicAdd(&deg[dst[i]], 1);
            rank[i] = (unsigned short)r;
        }
    }
}

// ---------------- 3-phase exclusive scan of deg -> offsets ----------------
__global__ __launch_bounds__(256) void k_scan_partial(const int* __restrict__ deg, int* __restrict__ partial) {
    __shared__ int sd[256];
    int i = blockIdx.x * 256 + threadIdx.x;
    sd[threadIdx.x] = (i < NN) ? deg[i] : 0;
    __syncthreads();
    for (int s = 128; s > 0; s >>= 1) {
        if (threadIdx.x < s) sd[threadIdx.x] += sd[threadIdx.x + s];
        __syncthreads();
    }
    if (threadIdx.x == 0) partial[blockIdx.x] = sd[0];
}

__global__ __launch_bounds__(512) void k_scan_block(int* __restrict__ partial, int nb) {
    __shared__ int s[512];
    int t = threadIdx.x;
    s[t] = (t < nb) ? partial[t] : 0;
    __syncthreads();
    for (int off = 1; off < 512; off <<= 1) {
        int add = (t >= off) ? s[t - off] : 0;
        __syncthreads();
        s[t] += add;
        __syncthreads();
    }
    if (t < nb) partial[t] = s[t];
}

__global__ __launch_bounds__(256) void k_scan_final(const int* __restrict__ deg, const int* __restrict__ partialScan,
                                                   int* __restrict__ offsets, float* __restrict__ inv_deg) {
    __shared__ int s[256];
    int b = blockIdx.x, t = threadIdx.x;
    int i = b * 256 + t;
    int v = (i < NN) ? deg[i] : 0;
    s[t] = v;
    __syncthreads();
    for (int off = 1; off < 256; off <<= 1) {
        int add = (t >= off) ? s[t - off] : 0;
        __syncthreads();
        s[t] += add;
        __syncthreads();
    }
    if (i < NN) {
        int base = (b > 0) ? partialScan[b - 1] : 0;
        int excl = base + s[t] - v;
        offsets[i] = excl;
        inv_deg[i] = (v > 0) ? (1.0f / (float)v) : 0.0f;
        if (i == NN - 1) offsets[NN] = excl + v;
    }
}

// ---------------- CSR fill: atomic-free fire-and-forget scatter ----------------
__global__ __launch_bounds__(256) void k_fill_csr(const int* __restrict__ src, const int* __restrict__ dst,
                                                  const unsigned short* __restrict__ rank,
                                                  const int* __restrict__ offsets,
                                                  int* __restrict__ sorted_src) {
    int base = blockIdx.x * 1024 + threadIdx.x;
#pragma unroll
    for (int k = 0; k < 4; k++) {
        int i = base + k * 256;
        if (i < NE) {
            int d = dst[i];
            int p = offsets[d] + (int)rank[i];
            sorted_src[p] = src[i];
        }
    }
}

// ---------------- mean aggregation: one wave per node, lane = feature ----------------
__global__ __launch_bounds__(256) void k_aggregate(const float* __restrict__ feat, const int* __restrict__ sorted_src,
                                                   const int* __restrict__ offsets, const float* __restrict__ inv_deg,
                                                   float* __restrict__ out) {
    int node = blockIdx.x * 4 + (threadIdx.x >> 6);
    int lane = threadIdx.x & 63;
    if (node >= NN) return;
    int beg = offsets[node], end = offsets[node + 1];
    float acc = 0.f;
    int e = beg;
    for (; e + 3 < end; e += 4) {
        int s0 = sorted_src[e], s1 = sorted_src[e + 1], s2 = sorted_src[e + 2], s3 = sorted_src[e + 3];
        acc += feat[(size_t)s0 * 64 + lane];
        acc += feat[(size_t)s1 * 64 + lane];
        acc += feat[(size_t)s2 * 64 + lane];
        acc += feat[(size_t)s3 * 64 + lane];
    }
    for (; e < end; e++) acc += feat[(size_t)sorted_src[e] * 64 + lane];
    out[(size_t)node * 64 + lane] = acc * inv_deg[node];
}

// ---------------- fused dual GEMM: out = relu(A1@W1 + b + A2@W2), optional @Wfc+bfc head ----------------
template <bool FUSE_HEAD>
__global__ __launch_bounds__(256) void k_linear(const float* __restrict__ A1, const float* __restrict__ A2,
                                                const float* __restrict__ W1, const float* __restrict__ W2,
                                                const float* __restrict__ bias,
                                                const float* __restrict__ Wfc, const float* __restrict__ bfc,
                                                float* __restrict__ out) {
    __shared__ __align__(16) float sA1[64 * 65];
    __shared__ __align__(16) float sA2[64 * 65];
    __shared__ __align__(16) float sW1[64 * 64];
    __shared__ __align__(16) float sW2[64 * 64];
    __shared__ float sB[64];
    __shared__ float sWfc[64];
    __shared__ float sRed[64 * 17];

    int tid = threadIdx.x;
    int i0 = blockIdx.x * 64;

#pragma unroll
    for (int r = 0; r < 4; r++) {
        int idx = r * 1024 + tid * 4;
        *(float4*)&sW1[idx] = *(const float4*)&W1[idx];
        *(float4*)&sW2[idx] = *(const float4*)&W2[idx];
    }
    if (tid < 64) {
        sB[tid] = bias[tid];
        sWfc[tid] = FUSE_HEAD ? Wfc[tid] : 0.f;
    }

    int col4 = (tid & 15) * 4;
#pragma unroll
    for (int rep = 0; rep < 4; rep++) {
        int r = rep * 16 + (tid >> 4);
        int g = i0 + r;
        float4 v1 = {0, 0, 0, 0}, v2 = {0, 0, 0, 0};
        if (g < NN) {
            v1 = *(const float4*)&A1[(size_t)g * 64 + col4];
            v2 = *(const float4*)&A2[(size_t)g * 64 + col4];
        }
        sA1[r * 65 + col4 + 0] = v1.x; sA1[r * 65 + col4 + 1] = v1.y;
        sA1[r * 65 + col4 + 2] = v1.z; sA1[r * 65 + col4 + 3] = v1.w;
        sA2[r * 65 + col4 + 0] = v2.x; sA2[r * 65 + col4 + 1] = v2.y;
        sA2[r * 65 + col4 + 2] = v2.z; sA2[r * 65 + col4 + 3] = v2.w;
    }
    __syncthreads();

    int tj = tid & 15;
    int ti = tid >> 4;
    float acc[4][4] = {};
    const float4* W1f = (const float4*)sW1;
    const float4* W2f = (const float4*)sW2;
#pragma unroll 8
    for (int k = 0; k < 64; k++) {
        float4 w1 = W1f[k * 16 + tj];
        float4 w2 = W2f[k * 16 + tj];
#pragma unroll
        for (int d = 0; d < 4; d++) {
            float a1 = sA1[(ti * 4 + d) * 65 + k];
            float a2 = sA2[(ti * 4 + d) * 65 + k];
            acc[d][0] += a1 * w1.x; acc[d][0] += a2 * w2.x;
            acc[d][1] += a1 * w1.y; acc[d][1] += a2 * w2.y;
            acc[d][2] += a1 * w1.z; acc[d][2] += a2 * w2.z;
            acc[d][3] += a1 * w1.w; acc[d][3] += a2 * w2.w;
        }
    }

    if (!FUSE_HEAD) {
#pragma unroll
        for (int d = 0; d < 4; d++) {
            int g = i0 + ti * 4 + d;
            if (g < NN) {
                float4 o;
                o.x = fmaxf(acc[d][0] + sB[tj * 4 + 0], 0.f);
                o.y = fmaxf(acc[d][1] + sB[tj * 4 + 1], 0.f);
                o.z = fmaxf(acc[d][2] + sB[tj * 4 + 2], 0.f);
                o.w = fmaxf(acc[d][3] + sB[tj * 4 + 3], 0.f);
                *(float4*)&out[(size_t)g * 64 + tj * 4] = o;
            }
        }
    } else {
#pragma unroll
        for (int d = 0; d < 4; d++) {
            float psum = 0.f;
            psum += fmaxf(acc[d][0] + sB[tj * 4 + 0], 0.f) * sWfc[tj * 4 + 0];
            psum += fmaxf(acc[d][1] + sB[tj * 4 + 1], 0.f) * sWfc[tj * 4 + 1];
            psum += fmaxf(acc[d][2] + sB[tj * 4 + 2], 0.f) * sWfc[tj * 4 + 2];
            psum += fmaxf(acc[d][3] + sB[tj * 4 + 3], 0.f) * sWfc[tj * 4 + 3];
            sRed[(ti * 4 + d) * 17 + tj] = psum;
        }
        __syncthreads();
        if (tid < 64) {
            float sum = bfc[0];
#pragma unroll
            for (int c = 0; c < 16; c++) sum += sRed[tid * 17 + c];
            int g = i0 + tid;
            if (g < NN) out[g] = sum;
        }
    }
}

extern "C" void kernel_launch(void* const* d_in, const int* in_sizes, int n_in,
                              void* d_out, int out_size, void* d_ws, size_t ws_size,
                              hipStream_t stream) {
    const float* x   = (const float*)d_in[0];
    const int*   ei  = (const int*)d_in[1];
    const float* Wl1 = (const float*)d_in[2];
    const float* bl1 = (const float*)d_in[3];
    const float* Wr1 = (const float*)d_in[4];
    const float* Wl2 = (const float*)d_in[5];
    const float* bl2 = (const float*)d_in[6];
    const float* Wr2 = (const float*)d_in[7];
    const float* Wfc = (const float*)d_in[8];
    const float* bfc = (const float*)d_in[9];
    float* out = (float*)d_out;

    const int* src = ei;       // edge_index[0]
    const int* dst = ei + NE;  // edge_index[1]

    char* p = (char*)d_ws;
    auto carve = [&](size_t bytes) {
        char* q = p;
        p += (bytes + 255) & ~size_t(255);
        return q;
    };
    int*            deg     = (int*)carve((size_t)NN * 4);
    int*            offsets = (int*)carve((size_t)(NN + 1) * 4);
    int*            partial = (int*)carve(512 * 4);
    float*          inv_deg = (float*)carve((size_t)NN * 4);
    unsigned short* rank    = (unsigned short*)carve((size_t)NE * 2);
    int*            ssrc    = (int*)carve((size_t)NE * 4);
    float*          agg     = (float*)carve((size_t)NN * 64 * 4);
    float*          h1      = (float*)carve((size_t)NN * 64 * 4);

    const int ebl4 = (NE + 1023) / 1024;  // 1563 (4 edges/thread)
    const int nbl  = (NN + 255) / 256;    // 391

    hipMemsetAsync(deg, 0, (size_t)NN * 4, stream);
    k_count_rank<<<ebl4, 256, 0, stream>>>(dst, deg, rank);
    k_scan_partial<<<nbl, 256, 0, stream>>>(deg, partial);
    k_scan_block<<<1, 512, 0, stream>>>(partial, nbl);
    k_scan_final<<<nbl, 256, 0, stream>>>(deg, partial, offsets, inv_deg);
    k_fill_csr<<<ebl4, 256, 0, stream>>>(src, dst, rank, offsets, ssrc);

    // layer 1
    k_aggregate<<<(NN + 3) / 4, 256, 0, stream>>>(x, ssrc, offsets, inv_deg, agg);
    k_linear<false><<<(NN + 63) / 64, 256, 0, stream>>>(agg, x, Wl1, Wr1, bl1, Wfc, bfc, h1);
    // layer 2 + fused head
    k_aggregate<<<(NN + 3) / 4, 256, 0, stream>>>(h1, ssrc, offsets, inv_deg, agg);
    k_linear<true><<<(NN + 63) / 64, 256, 0, stream>>>(agg, h1, Wl2, Wr2, bl2, Wfc, bfc, out);
}

// Round 3
// 380.490 us; speedup vs baseline: 1.2994x; 1.0354x over previous
//
#include <hip/hip_runtime.h>

#define NN 100000
#define NE 1600000

// ---------------- degree count + per-edge rank (rank = atomic return) ----------------
__global__ __launch_bounds__(256) void k_count_rank(const int* __restrict__ dst, int* __restrict__ deg,
                                                    unsigned short* __restrict__ rank) {
    int base = blockIdx.x * 2048 + threadIdx.x;
#pragma unroll
    for (int k = 0; k < 8; k++) {
        int i = base + k * 256;
        if (i < NE) {
            int r = atomicAdd(&deg[dst[i]], 1);
            rank[i] = (unsigned short)r;
        }
    }
}

// ---------------- 3-phase exclusive scan of deg -> offsets ----------------
__global__ __launch_bounds__(256) void k_scan_partial(const int* __restrict__ deg, int* __restrict__ partial) {
    __shared__ int sd[256];
    int i = blockIdx.x * 256 + threadIdx.x;
    sd[threadIdx.x] = (i < NN) ? deg[i] : 0;
    __syncthreads();
    for (int s = 128; s > 0; s >>= 1) {
        if (threadIdx.x < s) sd[threadIdx.x] += sd[threadIdx.x + s];
        __syncthreads();
    }
    if (threadIdx.x == 0) partial[blockIdx.x] = sd[0];
}

__global__ __launch_bounds__(512) void k_scan_block(int* __restrict__ partial, int nb) {
    __shared__ int s[512];
    int t = threadIdx.x;
    s[t] = (t < nb) ? partial[t] : 0;
    __syncthreads();
    for (int off = 1; off < 512; off <<= 1) {
        int add = (t >= off) ? s[t - off] : 0;
        __syncthreads();
        s[t] += add;
        __syncthreads();
    }
    if (t < nb) partial[t] = s[t];
}

__global__ __launch_bounds__(256) void k_scan_final(const int* __restrict__ deg, const int* __restrict__ partialScan,
                                                   int* __restrict__ offsets, float* __restrict__ inv_deg) {
    __shared__ int s[256];
    int b = blockIdx.x, t = threadIdx.x;
    int i = b * 256 + t;
    int v = (i < NN) ? deg[i] : 0;
    s[t] = v;
    __syncthreads();
    for (int off = 1; off < 256; off <<= 1) {
        int add = (t >= off) ? s[t - off] : 0;
        __syncthreads();
        s[t] += add;
        __syncthreads();
    }
    if (i < NN) {
        int base = (b > 0) ? partialScan[b - 1] : 0;
        int excl = base + s[t] - v;
        offsets[i] = excl;
        inv_deg[i] = (v > 0) ? (1.0f / (float)v) : 0.0f;
        if (i == NN - 1) offsets[NN] = excl + v;
    }
}

// ---------------- CSR fill: atomic-free fire-and-forget scatter ----------------
__global__ __launch_bounds__(256) void k_fill_csr(const int* __restrict__ src, const int* __restrict__ dst,
                                                  const unsigned short* __restrict__ rank,
                                                  const int* __restrict__ offsets,
                                                  int* __restrict__ sorted_src) {
    int base = blockIdx.x * 1024 + threadIdx.x;
#pragma unroll
    for (int k = 0; k < 4; k++) {
        int i = base + k * 256;
        if (i < NE) {
            int d = dst[i];
            int p = offsets[d] + (int)rank[i];
            sorted_src[p] = src[i];
        }
    }
}

// ---------------- mean aggregation: one wave per node, lane = feature ----------------
// 16 gathers in flight per wave, 4 independent accumulator chains.
__global__ __launch_bounds__(256) void k_aggregate(const float* __restrict__ feat, const int* __restrict__ sorted_src,
                                                   const int* __restrict__ offsets, const float* __restrict__ inv_deg,
                                                   float* __restrict__ out) {
    int node = blockIdx.x * 4 + (threadIdx.x >> 6);
    int lane = threadIdx.x & 63;
    if (node >= NN) return;
    int beg = offsets[node], end = offsets[node + 1];
    float a0 = 0.f, a1 = 0.f, a2 = 0.f, a3 = 0.f;
    int e = beg;

    for (; e + 16 <= end; e += 16) {
        int idx[16];
#pragma unroll
        for (int k = 0; k < 16; k++) idx[k] = sorted_src[e + k];
        float v[16];
#pragma unroll
        for (int k = 0; k < 16; k++) v[k] = feat[(size_t)idx[k] * 64 + lane];
#pragma unroll
        for (int k = 0; k < 16; k += 4) {
            a0 += v[k]; a1 += v[k + 1]; a2 += v[k + 2]; a3 += v[k + 3];
        }
    }
    for (; e + 4 <= end; e += 4) {
        int i0 = sorted_src[e], i1 = sorted_src[e + 1], i2 = sorted_src[e + 2], i3 = sorted_src[e + 3];
        a0 += feat[(size_t)i0 * 64 + lane];
        a1 += feat[(size_t)i1 * 64 + lane];
        a2 += feat[(size_t)i2 * 64 + lane];
        a3 += feat[(size_t)i3 * 64 + lane];
    }
    for (; e < end; e++) a0 += feat[(size_t)sorted_src[e] * 64 + lane];
    out[(size_t)node * 64 + lane] = ((a0 + a1) + (a2 + a3)) * inv_deg[node];
}

// ---------------- fused dual GEMM: out = relu(A1@W1 + b + A2@W2), optional @Wfc+bfc head ----------------
template <bool FUSE_HEAD>
__global__ __launch_bounds__(256) void k_linear(const float* __restrict__ A1, const float* __restrict__ A2,
                                                const float* __restrict__ W1, const float* __restrict__ W2,
                                                const float* __restrict__ bias,
                                                const float* __restrict__ Wfc, const float* __restrict__ bfc,
                                                float* __restrict__ out) {
    __shared__ __align__(16) float sA1[64 * 65];
    __shared__ __align__(16) float sA2[64 * 65];
    __shared__ __align__(16) float sW1[64 * 64];
    __shared__ __align__(16) float sW2[64 * 64];
    __shared__ float sB[64];
    __shared__ float sWfc[64];
    __shared__ float sRed[64 * 17];

    int tid = threadIdx.x;
    int i0 = blockIdx.x * 64;

#pragma unroll
    for (int r = 0; r < 4; r++) {
        int idx = r * 1024 + tid * 4;
        *(float4*)&sW1[idx] = *(const float4*)&W1[idx];
        *(float4*)&sW2[idx] = *(const float4*)&W2[idx];
    }
    if (tid < 64) {
        sB[tid] = bias[tid];
        sWfc[tid] = FUSE_HEAD ? Wfc[tid] : 0.f;
    }

    int col4 = (tid & 15) * 4;
#pragma unroll
    for (int rep = 0; rep < 4; rep++) {
        int r = rep * 16 + (tid >> 4);
        int g = i0 + r;
        float4 v1 = {0, 0, 0, 0}, v2 = {0, 0, 0, 0};
        if (g < NN) {
            v1 = *(const float4*)&A1[(size_t)g * 64 + col4];
            v2 = *(const float4*)&A2[(size_t)g * 64 + col4];
        }
        sA1[r * 65 + col4 + 0] = v1.x; sA1[r * 65 + col4 + 1] = v1.y;
        sA1[r * 65 + col4 + 2] = v1.z; sA1[r * 65 + col4 + 3] = v1.w;
        sA2[r * 65 + col4 + 0] = v2.x; sA2[r * 65 + col4 + 1] = v2.y;
        sA2[r * 65 + col4 + 2] = v2.z; sA2[r * 65 + col4 + 3] = v2.w;
    }
    __syncthreads();

    int tj = tid & 15;
    int ti = tid >> 4;
    float acc[4][4] = {};
    const float4* W1f = (const float4*)sW1;
    const float4* W2f = (const float4*)sW2;
#pragma unroll 8
    for (int k = 0; k < 64; k++) {
        float4 w1 = W1f[k * 16 + tj];
        float4 w2 = W2f[k * 16 + tj];
#pragma unroll
        for (int d = 0; d < 4; d++) {
            float a1 = sA1[(ti * 4 + d) * 65 + k];
            float a2 = sA2[(ti * 4 + d) * 65 + k];
            acc[d][0] += a1 * w1.x; acc[d][0] += a2 * w2.x;
            acc[d][1] += a1 * w1.y; acc[d][1] += a2 * w2.y;
            acc[d][2] += a1 * w1.z; acc[d][2] += a2 * w2.z;
            acc[d][3] += a1 * w1.w; acc[d][3] += a2 * w2.w;
        }
    }

    if (!FUSE_HEAD) {
#pragma unroll
        for (int d = 0; d < 4; d++) {
            int g = i0 + ti * 4 + d;
            if (g < NN) {
                float4 o;
                o.x = fmaxf(acc[d][0] + sB[tj * 4 + 0], 0.f);
                o.y = fmaxf(acc[d][1] + sB[tj * 4 + 1], 0.f);
                o.z = fmaxf(acc[d][2] + sB[tj * 4 + 2], 0.f);
                o.w = fmaxf(acc[d][3] + sB[tj * 4 + 3], 0.f);
                *(float4*)&out[(size_t)g * 64 + tj * 4] = o;
            }
        }
    } else {
#pragma unroll
        for (int d = 0; d < 4; d++) {
            float psum = 0.f;
            psum += fmaxf(acc[d][0] + sB[tj * 4 + 0], 0.f) * sWfc[tj * 4 + 0];
            psum += fmaxf(acc[d][1] + sB[tj * 4 + 1], 0.f) * sWfc[tj * 4 + 1];
            psum += fmaxf(acc[d][2] + sB[tj * 4 + 2], 0.f) * sWfc[tj * 4 + 2];
            psum += fmaxf(acc[d][3] + sB[tj * 4 + 3], 0.f) * sWfc[tj * 4 + 3];
            sRed[(ti * 4 + d) * 17 + tj] = psum;
        }
        __syncthreads();
        if (tid < 64) {
            float sum = bfc[0];
#pragma unroll
            for (int c = 0; c < 16; c++) sum += sRed[tid * 17 + c];
            int g = i0 + tid;
            if (g < NN) out[g] = sum;
        }
    }
}

extern "C" void kernel_launch(void* const* d_in, const int* in_sizes, int n_in,
                              void* d_out, int out_size, void* d_ws, size_t ws_size,
                              hipStream_t stream) {
    const float* x   = (const float*)d_in[0];
    const int*   ei  = (const int*)d_in[1];
    const float* Wl1 = (const float*)d_in[2];
    const float* bl1 = (const float*)d_in[3];
    const float* Wr1 = (const float*)d_in[4];
    const float* Wl2 = (const float*)d_in[5];
    const float* bl2 = (const float*)d_in[6];
    const float* Wr2 = (const float*)d_in[7];
    const float* Wfc = (const float*)d_in[8];
    const float* bfc = (const float*)d_in[9];
    float* out = (float*)d_out;

    const int* src = ei;       // edge_index[0]
    const int* dst = ei + NE;  // edge_index[1]

    char* p = (char*)d_ws;
    auto carve = [&](size_t bytes) {
        char* q = p;
        p += (bytes + 255) & ~size_t(255);
        return q;
    };
    int*            deg     = (int*)carve((size_t)NN * 4);
    int*            offsets = (int*)carve((size_t)(NN + 1) * 4);
    int*            partial = (int*)carve(512 * 4);
    float*          inv_deg = (float*)carve((size_t)NN * 4);
    unsigned short* rank    = (unsigned short*)carve((size_t)NE * 2);
    int*            ssrc    = (int*)carve((size_t)NE * 4);
    float*          agg     = (float*)carve((size_t)NN * 64 * 4);
    float*          h1      = (float*)carve((size_t)NN * 64 * 4);

    const int ebl4 = (NE + 1023) / 1024;  // 4 edges/thread
    const int ebl8 = (NE + 2047) / 2048;  // 8 edges/thread
    const int nbl  = (NN + 255) / 256;

    hipMemsetAsync(deg, 0, (size_t)NN * 4, stream);
    k_count_rank<<<ebl8, 256, 0, stream>>>(dst, deg, rank);
    k_scan_partial<<<nbl, 256, 0, stream>>>(deg, partial);
    k_scan_block<<<1, 512, 0, stream>>>(partial, nbl);
    k_scan_final<<<nbl, 256, 0, stream>>>(deg, partial, offsets, inv_deg);
    k_fill_csr<<<ebl4, 256, 0, stream>>>(src, dst, rank, offsets, ssrc);

    // layer 1
    k_aggregate<<<(NN + 3) / 4, 256, 0, stream>>>(x, ssrc, offsets, inv_deg, agg);
    k_linear<false><<<(NN + 63) / 64, 256, 0, stream>>>(agg, x, Wl1, Wr1, bl1, Wfc, bfc, h1);
    // layer 2 + fused head
    k_aggregate<<<(NN + 3) / 4, 256, 0, stream>>>(h1, ssrc, offsets, inv_deg, agg);
    k_linear<true><<<(NN + 63) / 64, 256, 0, stream>>>(agg, h1, Wl2, Wr2, bl2, Wfc, bfc, out);
}

// Round 4
// 378.427 us; speedup vs baseline: 1.3065x; 1.0055x over previous
//
#include <hip/hip_runtime.h>

#define NN 100000
#define NE 1600000
#define NPART 8

// ---------------- degree count + per-edge rank, 8-way privatized by blockIdx%8 ----------------
// Partition p = blockIdx & 7 tracks the round-robin block->XCD mapping so atomics stay XCD-local.
__global__ __launch_bounds__(256) void k_count_rank(const int* __restrict__ dst, int* __restrict__ degp,
                                                    unsigned short* __restrict__ rank) {
    int p = blockIdx.x & (NPART - 1);
    int* mydeg = degp + (size_t)p * NN;
    int base = blockIdx.x * 1024 + threadIdx.x;
#pragma unroll
    for (int k = 0; k < 4; k++) {
        int i = base + k * 256;
        if (i < NE) {
            int r = atomicAdd(&mydeg[dst[i]], 1);
            rank[i] = (unsigned short)r;
        }
    }
}

// ---------------- 3-phase exclusive scan over total degree ----------------
__global__ __launch_bounds__(256) void k_scan_partial(const int* __restrict__ degp, int* __restrict__ partial) {
    __shared__ int sd[256];
    int i = blockIdx.x * 256 + threadIdx.x;
    int v = 0;
    if (i < NN) {
#pragma unroll
        for (int p = 0; p < NPART; p++) v += degp[(size_t)p * NN + i];
    }
    sd[threadIdx.x] = v;
    __syncthreads();
    for (int s = 128; s > 0; s >>= 1) {
        if (threadIdx.x < s) sd[threadIdx.x] += sd[threadIdx.x + s];
        __syncthreads();
    }
    if (threadIdx.x == 0) partial[blockIdx.x] = sd[0];
}

__global__ __launch_bounds__(512) void k_scan_block(int* __restrict__ partial, int nb) {
    __shared__ int s[512];
    int t = threadIdx.x;
    s[t] = (t < nb) ? partial[t] : 0;
    __syncthreads();
    for (int off = 1; off < 512; off <<= 1) {
        int add = (t >= off) ? s[t - off] : 0;
        __syncthreads();
        s[t] += add;
        __syncthreads();
    }
    if (t < nb) partial[t] = s[t];
}

__global__ __launch_bounds__(256) void k_scan_final(const int* __restrict__ degp, const int* __restrict__ partialScan,
                                                   int* __restrict__ offsets, int* __restrict__ pstart,
                                                   float* __restrict__ inv_deg) {
    __shared__ int s[256];
    int b = blockIdx.x, t = threadIdx.x;
    int i = b * 256 + t;
    int dp[NPART];
    int v = 0;
    if (i < NN) {
#pragma unroll
        for (int p = 0; p < NPART; p++) { dp[p] = degp[(size_t)p * NN + i]; v += dp[p]; }
    }
    s[t] = v;
    __syncthreads();
    for (int off = 1; off < 256; off <<= 1) {
        int add = (t >= off) ? s[t - off] : 0;
        __syncthreads();
        s[t] += add;
        __syncthreads();
    }
    if (i < NN) {
        int base = (b > 0) ? partialScan[b - 1] : 0;
        int excl = base + s[t] - v;
        offsets[i] = excl;
        inv_deg[i] = (v > 0) ? (1.0f / (float)v) : 0.0f;
        int run = excl;
#pragma unroll
        for (int p = 0; p < NPART; p++) { pstart[(size_t)p * NN + i] = run; run += dp[p]; }
        if (i == NN - 1) offsets[NN] = excl + v;
    }
}

// ---------------- CSR fill: atomic-free scatter; recover partition from edge->block mapping ----------------
__global__ __launch_bounds__(256) void k_fill_csr(const int* __restrict__ src, const int* __restrict__ dst,
                                                  const unsigned short* __restrict__ rank,
                                                  const int* __restrict__ pstart,
                                                  int* __restrict__ sorted_src) {
    int p = blockIdx.x & (NPART - 1);
    const int* mystart = pstart + (size_t)p * NN;
    int base = blockIdx.x * 1024 + threadIdx.x;
#pragma unroll
    for (int k = 0; k < 4; k++) {
        int i = base + k * 256;
        if (i < NE) {
            int d = dst[i];
            int pos = mystart[d] + (int)rank[i];
            sorted_src[pos] = src[i];
        }
    }
}

// ---------------- mean aggregation: one wave per node, lane = feature ----------------
__global__ __launch_bounds__(256) void k_aggregate(const float* __restrict__ feat, const int* __restrict__ sorted_src,
                                                   const int* __restrict__ offsets, const float* __restrict__ inv_deg,
                                                   float* __restrict__ out) {
    int node = blockIdx.x * 4 + (threadIdx.x >> 6);
    int lane = threadIdx.x & 63;
    if (node >= NN) return;
    int beg = offsets[node], end = offsets[node + 1];
    float a0 = 0.f, a1 = 0.f, a2 = 0.f, a3 = 0.f;
    int e = beg;

    for (; e + 16 <= end; e += 16) {
        int idx[16];
#pragma unroll
        for (int k = 0; k < 16; k++) idx[k] = sorted_src[e + k];
        float v[16];
#pragma unroll
        for (int k = 0; k < 16; k++) v[k] = feat[(size_t)idx[k] * 64 + lane];
#pragma unroll
        for (int k = 0; k < 16; k += 4) {
            a0 += v[k]; a1 += v[k + 1]; a2 += v[k + 2]; a3 += v[k + 3];
        }
    }
    for (; e + 4 <= end; e += 4) {
        int i0 = sorted_src[e], i1 = sorted_src[e + 1], i2 = sorted_src[e + 2], i3 = sorted_src[e + 3];
        a0 += feat[(size_t)i0 * 64 + lane];
        a1 += feat[(size_t)i1 * 64 + lane];
        a2 += feat[(size_t)i2 * 64 + lane];
        a3 += feat[(size_t)i3 * 64 + lane];
    }
    for (; e < end; e++) a0 += feat[(size_t)sorted_src[e] * 64 + lane];
    out[(size_t)node * 64 + lane] = ((a0 + a1) + (a2 + a3)) * inv_deg[node];
}

// ---------------- fused dual GEMM: out = relu(A1@W1 + b + A2@W2), optional @Wfc+bfc head ----------------
template <bool FUSE_HEAD>
__global__ __launch_bounds__(256) void k_linear(const float* __restrict__ A1, const float* __restrict__ A2,
                                                const float* __restrict__ W1, const float* __restrict__ W2,
                                                const float* __restrict__ bias,
                                                const float* __restrict__ Wfc, const float* __restrict__ bfc,
                                                float* __restrict__ out) {
    __shared__ __align__(16) float sA1[64 * 65];
    __shared__ __align__(16) float sA2[64 * 65];
    __shared__ __align__(16) float sW1[64 * 64];
    __shared__ __align__(16) float sW2[64 * 64];
    __shared__ float sB[64];
    __shared__ float sWfc[64];
    __shared__ float sRed[64 * 17];

    int tid = threadIdx.x;
    int i0 = blockIdx.x * 64;

#pragma unroll
    for (int r = 0; r < 4; r++) {
        int idx = r * 1024 + tid * 4;
        *(float4*)&sW1[idx] = *(const float4*)&W1[idx];
        *(float4*)&sW2[idx] = *(const float4*)&W2[idx];
    }
    if (tid < 64) {
        sB[tid] = bias[tid];
        sWfc[tid] = FUSE_HEAD ? Wfc[tid] : 0.f;
    }

    int col4 = (tid & 15) * 4;
#pragma unroll
    for (int rep = 0; rep < 4; rep++) {
        int r = rep * 16 + (tid >> 4);
        int g = i0 + r;
        float4 v1 = {0, 0, 0, 0}, v2 = {0, 0, 0, 0};
        if (g < NN) {
            v1 = *(const float4*)&A1[(size_t)g * 64 + col4];
            v2 = *(const float4*)&A2[(size_t)g * 64 + col4];
        }
        sA1[r * 65 + col4 + 0] = v1.x; sA1[r * 65 + col4 + 1] = v1.y;
        sA1[r * 65 + col4 + 2] = v1.z; sA1[r * 65 + col4 + 3] = v1.w;
        sA2[r * 65 + col4 + 0] = v2.x; sA2[r * 65 + col4 + 1] = v2.y;
        sA2[r * 65 + col4 + 2] = v2.z; sA2[r * 65 + col4 + 3] = v2.w;
    }
    __syncthreads();

    int tj = tid & 15;
    int ti = tid >> 4;
    float acc[4][4] = {};
    const float4* W1f = (const float4*)sW1;
    const float4* W2f = (const float4*)sW2;
#pragma unroll 8
    for (int k = 0; k < 64; k++) {
        float4 w1 = W1f[k * 16 + tj];
        float4 w2 = W2f[k * 16 + tj];
#pragma unroll
        for (int d = 0; d < 4; d++) {
            float a1 = sA1[(ti * 4 + d) * 65 + k];
            float a2 = sA2[(ti * 4 + d) * 65 + k];
            acc[d][0] += a1 * w1.x; acc[d][0] += a2 * w2.x;
            acc[d][1] += a1 * w1.y; acc[d][1] += a2 * w2.y;
            acc[d][2] += a1 * w1.z; acc[d][2] += a2 * w2.z;
            acc[d][3] += a1 * w1.w; acc[d][3] += a2 * w2.w;
        }
    }

    if (!FUSE_HEAD) {
#pragma unroll
        for (int d = 0; d < 4; d++) {
            int g = i0 + ti * 4 + d;
            if (g < NN) {
                float4 o;
                o.x = fmaxf(acc[d][0] + sB[tj * 4 + 0], 0.f);
                o.y = fmaxf(acc[d][1] + sB[tj * 4 + 1], 0.f);
                o.z = fmaxf(acc[d][2] + sB[tj * 4 + 2], 0.f);
                o.w = fmaxf(acc[d][3] + sB[tj * 4 + 3], 0.f);
                *(float4*)&out[(size_t)g * 64 + tj * 4] = o;
            }
        }
    } else {
#pragma unroll
        for (int d = 0; d < 4; d++) {
            float psum = 0.f;
            psum += fmaxf(acc[d][0] + sB[tj * 4 + 0], 0.f) * sWfc[tj * 4 + 0];
            psum += fmaxf(acc[d][1] + sB[tj * 4 + 1], 0.f) * sWfc[tj * 4 + 1];
            psum += fmaxf(acc[d][2] + sB[tj * 4 + 2], 0.f) * sWfc[tj * 4 + 2];
            psum += fmaxf(acc[d][3] + sB[tj * 4 + 3], 0.f) * sWfc[tj * 4 + 3];
            sRed[(ti * 4 + d) * 17 + tj] = psum;
        }
        __syncthreads();
        if (tid < 64) {
            float sum = bfc[0];
#pragma unroll
            for (int c = 0; c < 16; c++) sum += sRed[tid * 17 + c];
            int g = i0 + tid;
            if (g < NN) out[g] = sum;
        }
    }
}

extern "C" void kernel_launch(void* const* d_in, const int* in_sizes, int n_in,
                              void* d_out, int out_size, void* d_ws, size_t ws_size,
                              hipStream_t stream) {
    const float* x   = (const float*)d_in[0];
    const int*   ei  = (const int*)d_in[1];
    const float* Wl1 = (const float*)d_in[2];
    const float* bl1 = (const float*)d_in[3];
    const float* Wr1 = (const float*)d_in[4];
    const float* Wl2 = (const float*)d_in[5];
    const float* bl2 = (const float*)d_in[6];
    const float* Wr2 = (const float*)d_in[7];
    const float* Wfc = (const float*)d_in[8];
    const float* bfc = (const float*)d_in[9];
    float* out = (float*)d_out;

    const int* src = ei;       // edge_index[0]
    const int* dst = ei + NE;  // edge_index[1]

    char* p = (char*)d_ws;
    auto carve = [&](size_t bytes) {
        char* q = p;
        p += (bytes + 255) & ~size_t(255);
        return q;
    };
    // Long-lived buffers
    int*   offsets = (int*)carve((size_t)(NN + 1) * 4);
    int*   partial = (int*)carve(512 * 4);
    float* inv_deg = (float*)carve((size_t)NN * 4);
    int*   ssrc    = (int*)carve((size_t)NE * 4);
    float* h1      = (float*)carve((size_t)NN * 64 * 4);
    float* agg     = (float*)carve((size_t)NN * 64 * 4);
    // Short-lived temporaries alias onto agg (dead before agg is first written in k_aggregate):
    // degp: NPART*NN ints (3.2 MB), pstart: NPART*NN ints (3.2 MB), rank: NE u16 (3.2 MB) = 9.6 MB < 25.6 MB
    int*            degp   = (int*)agg;
    int*            pstart = degp + (size_t)NPART * NN;
    unsigned short* rank   = (unsigned short*)(pstart + (size_t)NPART * NN);

    const int ebl4 = (NE + 1023) / 1024;  // 1563 blocks, 4 edges/thread
    const int nbl  = (NN + 255) / 256;    // 391

    hipMemsetAsync(degp, 0, (size_t)NPART * NN * 4, stream);
    k_count_rank<<<ebl4, 256, 0, stream>>>(dst, degp, rank);
    k_scan_partial<<<nbl, 256, 0, stream>>>(degp, partial);
    k_scan_block<<<1, 512, 0, stream>>>(partial, nbl);
    k_scan_final<<<nbl, 256, 0, stream>>>(degp, partial, offsets, pstart, inv_deg);
    k_fill_csr<<<ebl4, 256, 0, stream>>>(src, dst, rank, pstart, ssrc);

    // layer 1
    k_aggregate<<<(NN + 3) / 4, 256, 0, stream>>>(x, ssrc, offsets, inv_deg, agg);
    k_linear<false><<<(NN + 63) / 64, 256, 0, stream>>>(agg, x, Wl1, Wr1, bl1, Wfc, bfc, h1);
    // layer 2 + fused head
    k_aggregate<<<(NN + 3) / 4, 256, 0, stream>>>(h1, ssrc, offsets, inv_deg, agg);
    k_linear<true><<<(NN + 63) / 64, 256, 0, stream>>>(agg, h1, Wl2, Wr2, bl2, Wfc, bfc, out);
}